// Round 5
// baseline (805.589 us; speedup 1.0000x reference)
//
#include <hip/hip_runtime.h>

// Locally connected layer, fp32:
//   out[n,o,l] = sum_k x_unf[n,l,k] * w[o,l,k] + bias[o,l]
//   l = ho*62+wo, k = c*9+i*3+j, x_unf[n,l,k] = x[n,c,ho+i,wo+j]
//
// Block = 256 threads = 4 waves; block owns 4 consecutive l (wave w -> lbase+w).
// Per wave: full 64n x 64o GEMM for its l, 8x8 register tile per thread.
// K in 36 chunks of 8, double-buffered LDS (issue-early loads, write-late).
// Epilogue: LDS transpose -> float4 stores along l (fixes 3.8x write amp seen
// in R1), bias fused.

#define L_TOT 3844
#define K_TOT 288
#define KC 8
#define NCH 36          // 288/8
#define ROW 68          // 64 + 4 pad (rows stay 16B-aligned: 68*4 = 272)
#define TILE_F (4 * KC * ROW)   // 2176 floats: one buffer, one matrix (4 l's)

__global__ __launch_bounds__(256, 4)
void lc_fp32_kernel(const float* __restrict__ x,
                    const float* __restrict__ wgt,
                    const float* __restrict__ bias,
                    float* __restrict__ out) {
    // [buf0 X][buf0 W][buf1 X][buf1 W]; epilogue reuses all of it as Es[4][32][68]
    __shared__ __align__(16) float smem[4 * TILE_F];   // 34816 B
    __shared__ int offs[K_TOT];

    const int tid = threadIdx.x;

    for (int k = tid; k < K_TOT; k += 256) {
        int c = k / 9, r = k % 9;
        offs[k] = c * 4096 + (r / 3) * 64 + (r % 3);
    }

    // Bijective XCD swizzle over 961 l-groups (961 = 8*120 + 1, m204 formula)
    const int orig = blockIdx.x;
    const int xcd = orig & 7, slot = orig >> 3;
    const int lg = (xcd == 0) ? slot : (121 + (xcd - 1) * 120 + slot);
    const int lbase = lg * 4;

    // ---- staging index precompute ----
    // X chunk = 4l x 8k x 64n = 2048 elems, 8/thread:
    //   e=0..7: li=e>>1, k=tid&7, n=(e&1)*32 + (tid>>3)
    const int kq = tid & 7;
    const int t8 = tid >> 3;            // 0..31
    // W chunk = 4l x 8k x 64o = 512 float4, 2/thread:
    //   e=0..1: li=2e + (tid>>7), o=(tid>>1)&63, k-quad=tid&1
    const int ow  = (tid >> 1) & 63;
    const int th  = tid >> 7;           // 0..1
    const int k4w = tid & 1;

    int xb[4];                           // block-uniform x window base per li
#pragma unroll
    for (int li = 0; li < 4; ++li) {
        int l = lbase + li;
        xb[li] = (l / 62) * 64 + (l % 62);
    }
    const float* xP = x + t8 * 131072;                     // + n_low*C*H*W
    const int wgb = ow * (L_TOT * K_TOT) + (lbase + th) * K_TOT + k4w * 4;
    const int xw  = kq * ROW + t8;                         // X ds-write base
    const int wwb = th * 544 + k4w * 272 + ow;             // W ds-write base

    // ---- compute indices ----
    const int wv = tid >> 6;            // wave = local l
    const int lane = tid & 63;
    const int tx = lane & 7;            // o-octet
    const int ty = lane >> 3;           // n-octet

    float* Xb0 = smem;
    float* Wb0 = smem + TILE_F;
    float* Xb1 = smem + 2 * TILE_F;
    float* Wb1 = smem + 3 * TILE_F;

    float acc[8][8];
#pragma unroll
    for (int m = 0; m < 8; ++m)
#pragma unroll
        for (int j = 0; j < 8; ++j) acc[m][j] = 0.f;

    float xv[8];
    float4 wv4[2];

#define STAGE_LOAD(ch)                                                        \
    {                                                                         \
        const int kk = (ch) * KC;                                             \
        const int offk = offs[kk + kq];                                       \
        _Pragma("unroll")                                                     \
        for (int e = 0; e < 8; ++e)                                           \
            xv[e] = xP[(e & 1) * 4194304 + xb[e >> 1] + offk];                \
        wv4[0] = *(const float4*)(wgt + wgb + kk);                            \
        wv4[1] = *(const float4*)(wgt + wgb + 576 + kk);                      \
    }

#define STAGE_WRITE(XB, WB)                                                   \
    {                                                                         \
        _Pragma("unroll")                                                     \
        for (int e = 0; e < 8; ++e)                                           \
            XB[(e >> 1) * 544 + (e & 1) * 32 + xw] = xv[e];                   \
        _Pragma("unroll")                                                     \
        for (int e = 0; e < 2; ++e) {                                         \
            WB[wwb + e * 1088]       = wv4[e].x;                              \
            WB[wwb + e * 1088 + 68]  = wv4[e].y;                              \
            WB[wwb + e * 1088 + 136] = wv4[e].z;                              \
            WB[wwb + e * 1088 + 204] = wv4[e].w;                              \
        }                                                                     \
    }

#define COMPUTE(XB, WB)                                                       \
    {                                                                         \
        _Pragma("unroll")                                                     \
        for (int k = 0; k < KC; ++k) {                                        \
            const float4 a0 = *(const float4*)(XB + wv*544 + k*68 + ty*8);    \
            const float4 a1 = *(const float4*)(XB + wv*544 + k*68 + ty*8 + 4);\
            const float4 b0 = *(const float4*)(WB + wv*544 + k*68 + tx*8);    \
            const float4 b1 = *(const float4*)(WB + wv*544 + k*68 + tx*8 + 4);\
            const float av[8] = {a0.x,a0.y,a0.z,a0.w,a1.x,a1.y,a1.z,a1.w};    \
            const float bw[8] = {b0.x,b0.y,b0.z,b0.w,b1.x,b1.y,b1.z,b1.w};    \
            _Pragma("unroll")                                                 \
            for (int m = 0; m < 8; ++m)                                       \
                _Pragma("unroll")                                             \
                for (int j = 0; j < 8; ++j)                                   \
                    acc[m][j] = fmaf(av[m], bw[j], acc[m][j]);                \
        }                                                                     \
    }

    __syncthreads();                 // offs table ready
    STAGE_LOAD(0);
    STAGE_WRITE(Xb0, Wb0);
    __syncthreads();

    for (int ch = 0; ch < NCH; ch += 2) {
        STAGE_LOAD(ch + 1);          // ch+1 <= 35 always
        COMPUTE(Xb0, Wb0);           // hides load latency
        STAGE_WRITE(Xb1, Wb1);
        __syncthreads();
        if (ch + 2 < NCH) {
            STAGE_LOAD(ch + 2);
            COMPUTE(Xb1, Wb1);
            STAGE_WRITE(Xb0, Wb0);
        } else {
            COMPUTE(Xb1, Wb1);
        }
        __syncthreads();
    }

    // ---- epilogue: transpose via LDS so stores are float4 along l ----
    // Es[li][n'][ROW] (= 4*32*68 floats = whole smem), halves of n (32 rows).
    float* Es = smem;
    const int h_owner = ty >> 2;
    const int typ = ty & 3;
    const float4 bv4 = *(const float4*)(bias + lane * L_TOT + lbase);

#pragma unroll
    for (int h = 0; h < 2; ++h) {
        if (h == 1) __syncthreads();            // h=0 reads done before rewrite
        if (h_owner == h) {
#pragma unroll
            for (int m = 0; m < 8; ++m) {
                *(float4*)(Es + wv*2176 + (typ*8 + m)*68 + tx*8) =
                    make_float4(acc[m][0], acc[m][1], acc[m][2], acc[m][3]);
                *(float4*)(Es + wv*2176 + (typ*8 + m)*68 + tx*8 + 4) =
                    make_float4(acc[m][4], acc[m][5], acc[m][6], acc[m][7]);
            }
        }
        __syncthreads();
#pragma unroll
        for (int e = 0; e < 8; ++e) {
            const int np = e * 4 + wv;          // n' within half
            float4 sv;
            sv.x = Es[           np*68 + lane];
            sv.y = Es[1*2176 +   np*68 + lane];
            sv.z = Es[2*2176 +   np*68 + lane];
            sv.w = Es[3*2176 +   np*68 + lane];
            sv.x += bv4.x; sv.y += bv4.y; sv.z += bv4.z; sv.w += bv4.w;
            *(float4*)(out + ((h*32 + np)*64 + lane) * L_TOT + lbase) = sv;
        }
    }
}

extern "C" void kernel_launch(void* const* d_in, const int* in_sizes, int n_in,
                              void* d_out, int out_size, void* d_ws, size_t ws_size,
                              hipStream_t stream) {
    const float* x = (const float*)d_in[0];   // (64,32,64,64)
    const float* w = (const float*)d_in[1];   // (64,3844,288)
    const float* b = (const float*)d_in[2];   // (64,3844)
    float* out = (float*)d_out;               // (64,64,62,62)

    hipLaunchKernelGGL(lc_fp32_kernel, dim3(L_TOT / 4), dim3(256), 0, stream,
                       x, w, b, out);
}